// Round 1
// baseline (21828.473 us; speedup 1.0000x reference)
//
#include <hip/hip_runtime.h>
#include <math.h>

#define NX 8192
#define NY 65536
#define DIM 512
#define KNN 8

#define BX 64          // X rows per block
#define BYT 64         // Y cols per tile
#define KC 64          // K chunk staged in LDS
#define NCHUNK 32      // Y chunks (grid dim)
#define CHUNK_NY (NY / NCHUNK)    // 2048
#define NTILES (CHUNK_NY / BYT)   // 32

// Insert candidate (d, gi) into ascending-sorted (dist, idx) top-8 kept in
// registers. All indices compile-time constant (rule: runtime-indexed arrays
// go to scratch).
__device__ __forceinline__ void topk_push(float d, int gi, float bd[KNN], int bi[KNN]) {
    // reject common case with one compare
    if (d > bd[KNN - 1] || (d == bd[KNN - 1] && gi >= bi[KNN - 1])) return;
    bd[KNN - 1] = d; bi[KNN - 1] = gi;
#pragma unroll
    for (int p = KNN - 1; p > 0; --p) {
        bool sw = (bd[p] < bd[p - 1]) || (bd[p] == bd[p - 1] && bi[p] < bi[p - 1]);
        if (sw) {
            float td = bd[p]; bd[p] = bd[p - 1]; bd[p - 1] = td;
            int   ti = bi[p]; bi[p] = bi[p - 1]; bi[p - 1] = ti;
        }
    }
}

// ||y||^2 per Y row, fp64 accumulate, one wave per row.
__global__ void ysq_kernel(const float* __restrict__ Y, float* __restrict__ ysq) {
    int row = (blockIdx.x * blockDim.x + threadIdx.x) >> 6;
    int lane = threadIdx.x & 63;
    if (row >= NY) return;
    const float4* yr = reinterpret_cast<const float4*>(Y + (size_t)row * DIM);
    double s = 0.0;
#pragma unroll
    for (int i = 0; i < 2; ++i) {
        float4 v = yr[lane + 64 * i];
        s += (double)v.x * v.x + (double)v.y * v.y + (double)v.z * v.z + (double)v.w * v.w;
    }
#pragma unroll
    for (int off = 32; off > 0; off >>= 1) s += __shfl_xor(s, off, 64);
    if (lane == 0) ysq[row] = (float)s;
}

__global__ __launch_bounds__(256) void knn_phase1(
        const float* __restrict__ X, const float* __restrict__ Y,
        const float* __restrict__ ysq,
        float* __restrict__ cand_d, int* __restrict__ cand_i) {
    __shared__ float Xs[KC][BX];        // 16 KB, [k][row] transposed
    __shared__ float Ys[KC][BYT];       // 16 KB, [k][col] transposed
    __shared__ float Dt[BX][BYT + 4];   // 17.4 KB padded dist tile (also merge buf)

    const int tid   = threadIdx.x;
    const int chunk = blockIdx.x;       // 0..31
    const int xt    = blockIdx.y;       // 0..127
    const int row0  = xt * BX;
    const int ybase = chunk * CHUNK_NY;

    const int ty = tid >> 4;            // 0..15 -> rows ty*4..+3
    const int tx = tid & 15;            // cols tx*4..+3
    const int sr = tid >> 2;            // scan row 0..63
    const int sc = tid & 3;             // scan col class
    const int lr = tid & 63;            // staging row/col
    const int kq = tid >> 6;            // staging k-quarter

    float bd[KNN]; int bi[KNN];
#pragma unroll
    for (int m = 0; m < KNN; ++m) { bd[m] = INFINITY; bi[m] = 0x7fffffff; }

    for (int t = 0; t < NTILES; ++t) {
        const int col0 = ybase + t * BYT;

        double acc64[4][4];
#pragma unroll
        for (int i = 0; i < 4; ++i)
#pragma unroll
            for (int j = 0; j < 4; ++j) acc64[i][j] = 0.0;

        for (int kc = 0; kc < DIM; kc += KC) {
            __syncthreads();   // protect previous iteration's LDS reads
            // stage X,Y tiles transposed: thread (lr, kq) covers 16 k values
            {
                const float4* xg = reinterpret_cast<const float4*>(
                    X + (size_t)(row0 + lr) * DIM + kc + kq * 16);
                const float4* yg = reinterpret_cast<const float4*>(
                    Y + (size_t)(col0 + lr) * DIM + kc + kq * 16);
                float4 xv[4], yv[4];
#pragma unroll
                for (int q = 0; q < 4; ++q) { xv[q] = xg[q]; yv[q] = yg[q]; }
#pragma unroll
                for (int q = 0; q < 4; ++q) {
                    int k = kq * 16 + q * 4;
                    Xs[k + 0][lr] = xv[q].x; Xs[k + 1][lr] = xv[q].y;
                    Xs[k + 2][lr] = xv[q].z; Xs[k + 3][lr] = xv[q].w;
                    Ys[k + 0][lr] = yv[q].x; Ys[k + 1][lr] = yv[q].y;
                    Ys[k + 2][lr] = yv[q].z; Ys[k + 3][lr] = yv[q].w;
                }
            }
            __syncthreads();

            float acc[4][4];
#pragma unroll
            for (int i = 0; i < 4; ++i)
#pragma unroll
                for (int j = 0; j < 4; ++j) acc[i][j] = 0.0f;

#pragma unroll 16
            for (int k = 0; k < KC; ++k) {
                float4 a = *reinterpret_cast<const float4*>(&Xs[k][ty * 4]);
                float4 b = *reinterpret_cast<const float4*>(&Ys[k][tx * 4]);
                float ax[4] = {a.x, a.y, a.z, a.w};
                float bv[4] = {b.x, b.y, b.z, b.w};
#pragma unroll
                for (int i = 0; i < 4; ++i)
#pragma unroll
                    for (int j = 0; j < 4; ++j)
                        acc[i][j] = fmaf(ax[i], bv[j], acc[i][j]);
            }
#pragma unroll
            for (int i = 0; i < 4; ++i)
#pragma unroll
                for (int j = 0; j < 4; ++j) acc64[i][j] += (double)acc[i][j];
        }

        // dist tile: d = ysq[col] - 2*dot  (x_sq constant per row -> dropped)
        float ysqv[4];
#pragma unroll
        for (int j = 0; j < 4; ++j) ysqv[j] = ysq[col0 + tx * 4 + j];
#pragma unroll
        for (int i = 0; i < 4; ++i)
#pragma unroll
            for (int j = 0; j < 4; ++j)
                Dt[ty * 4 + i][tx * 4 + j] =
                    (float)((double)ysqv[j] - 2.0 * acc64[i][j]);
        __syncthreads();

        // top-8 scan: 4 threads per row, 16 cols each
#pragma unroll
        for (int q = 0; q < 16; ++q) {
            int c = sc + q * 4;
            float d = Dt[sr][c];
            topk_push(d, col0 + c, bd, bi);
        }
        // no sync needed: next Dt write is after the k-loop's barriers
    }

    // block merge: 4 threads per row -> 8 candidates per (row, chunk)
    float* buf = &Dt[0][0];   // 4352 floats >= 256*16
    __syncthreads();
#pragma unroll
    for (int m = 0; m < KNN; ++m) {
        buf[tid * 16 + m]       = bd[m];
        buf[tid * 16 + 8 + m]   = __int_as_float(bi[m]);
    }
    __syncthreads();
    if ((tid & 3) == 0) {
        float fd[KNN]; int fi[KNN];
#pragma unroll
        for (int m = 0; m < KNN; ++m) { fd[m] = INFINITY; fi[m] = 0x7fffffff; }
        for (int s = 0; s < 4; ++s) {
            int b = (tid + s) * 16;
#pragma unroll
            for (int m = 0; m < KNN; ++m)
                topk_push(buf[b + m], __float_as_int(buf[b + 8 + m]), fd, fi);
        }
        const int row = row0 + sr;
        const size_t o = ((size_t)row * NCHUNK + chunk) * KNN;
#pragma unroll
        for (int m = 0; m < KNN; ++m) { cand_d[o + m] = fd[m]; cand_i[o + m] = fi[m]; }
    }
}

__global__ void knn_phase2(const float* __restrict__ cand_d,
                           const int* __restrict__ cand_i,
                           int* __restrict__ out) {
    int row = blockIdx.x * blockDim.x + threadIdx.x;
    if (row >= NX) return;
    float bd[KNN]; int bi[KNN];
#pragma unroll
    for (int m = 0; m < KNN; ++m) { bd[m] = INFINITY; bi[m] = 0x7fffffff; }
    const size_t base = (size_t)row * NCHUNK * KNN;
    for (int c = 0; c < NCHUNK * KNN; ++c)
        topk_push(cand_d[base + c], cand_i[base + c], bd, bi);
#pragma unroll
    for (int m = 0; m < KNN; ++m) out[row * KNN + m] = bi[m];
}

extern "C" void kernel_launch(void* const* d_in, const int* in_sizes, int n_in,
                              void* d_out, int out_size, void* d_ws, size_t ws_size,
                              hipStream_t stream) {
    const float* X = (const float*)d_in[0];   // [8192, 512]
    const float* Y = (const float*)d_in[1];   // [65536, 512]
    int* out = (int*)d_out;                   // [8192, 8] int32

    char* ws = (char*)d_ws;
    float* ysq    = (float*)ws;                                   // 256 KB
    float* cand_d = (float*)(ws + (size_t)NY * sizeof(float));    // 8 MB
    int*   cand_i = (int*)(ws + (size_t)NY * sizeof(float)
                               + (size_t)NX * NCHUNK * KNN * sizeof(float)); // 8 MB

    ysq_kernel<<<NY / 4, 256, 0, stream>>>(Y, ysq);

    dim3 g1(NCHUNK, NX / BX);   // 32 x 128 blocks
    knn_phase1<<<g1, 256, 0, stream>>>(X, Y, ysq, cand_d, cand_i);

    knn_phase2<<<NX / 256, 256, 0, stream>>>(cand_d, cand_i, out);
}

// Round 4
// 3492.875 us; speedup vs baseline: 6.2494x; 6.2494x over previous
//
#include <hip/hip_runtime.h>
#include <math.h>

#define NX 8192
#define NY 65536
#define DIM 512
#define KNN 8

#define BM 128                 // Y rows per tile (MFMA M side)
#define BN 128                 // X rows per block (MFMA N side)
#define BK 64                  // K step
#define NCH 8                  // Y chunks (grid.x)
#define COLS_PER_CHUNK (NY / NCH)            // 8192 Y rows per chunk
#define TILES_PER_CHUNK (COLS_PER_CHUNK / BM)  // 64
#define LPT 8                  // per-lane top-K per X-row
#define KEEP 16                // kept per (row, chunk)
#define NCAND (NCH * KEEP)     // 128 candidates per row
#define RESC 32                // rescored per row

#define ST 160                 // LDS row stride in bytes (128 payload + 32 pad)

typedef short bf16x8 __attribute__((ext_vector_type(8)));
typedef float f32x4 __attribute__((ext_vector_type(4)));

__device__ __forceinline__ unsigned short f2b(float f) {
    unsigned int u = __float_as_uint(f);
    u += 0x7FFFu + ((u >> 16) & 1u);       // RNE to bf16
    return (unsigned short)(u >> 16);
}

// ascending (d, idx) top-K insert, fully static indices
template <int K>
__device__ __forceinline__ void push(float d, int gi, float (&bd)[K], int (&bi)[K]) {
    if (d > bd[K - 1] || (d == bd[K - 1] && gi >= bi[K - 1])) return;
    bd[K - 1] = d; bi[K - 1] = gi;
#pragma unroll
    for (int p = K - 1; p > 0; --p) {
        bool sw = (bd[p] < bd[p - 1]) || (bd[p] == bd[p - 1] && bi[p] < bi[p - 1]);
        if (sw) {
            float td = bd[p]; bd[p] = bd[p - 1]; bd[p - 1] = td;
            int   ti = bi[p]; bi[p] = bi[p - 1]; bi[p - 1] = ti;
        }
    }
}

// ||y||^2 per Y row, fp64 accumulate, one wave per row. (verified round 1)
__global__ void ysq_kernel(const float* __restrict__ Y, float* __restrict__ ysq) {
    int row  = (blockIdx.x * blockDim.x + threadIdx.x) >> 6;
    int lane = threadIdx.x & 63;
    if (row >= NY) return;
    const float4* yr = reinterpret_cast<const float4*>(Y + (size_t)row * DIM);
    double s = 0.0;
#pragma unroll
    for (int i = 0; i < 2; ++i) {
        float4 v = yr[lane + 64 * i];
        s += (double)v.x * v.x + (double)v.y * v.y + (double)v.z * v.z + (double)v.w * v.w;
    }
#pragma unroll
    for (int off = 32; off > 0; off >>= 1) s += __shfl_xor(s, off, 64);
    if (lane == 0) ysq[row] = (float)s;
}

// Coarse pass: G = Y_tile . X^T via bf16 MFMA; each lane pushes its acc
// elements (4 X-rows x 16 Y-cands per tile) into per-X-row top-8 lists.
// (unchanged from round 3 — inferred correct)
__global__ __launch_bounds__(256, 2) void knn_coarse(
        const float* __restrict__ X, const float* __restrict__ Y,
        const float* __restrict__ ysq,
        float* __restrict__ cand_d, int* __restrict__ cand_i) {
    __shared__ __align__(16) char smem[65536];
    char* As = smem;
    char* Bs = smem + 20480;
    float* ysq_s = (float*)(smem + 40960);

    const int tid  = threadIdx.x;
    const int lane = tid & 63;
    const int wv   = tid >> 6;
    const int chunk = blockIdx.x;            // 0..7
    const int row0  = blockIdx.y * BN;       // X rows of this block
    const int ybase = chunk * COLS_PER_CHUNK;
    const int m0 = (wv >> 1) * 64;           // wave quadrant: Y side
    const int n0 = (wv & 1) * 64;            //                X side
    const int l15 = lane & 15;
    const int lg  = lane >> 4;               // 0..3

    float bd[4][LPT]; int bi[4][LPT];
#pragma unroll
    for (int nf = 0; nf < 4; ++nf)
#pragma unroll
        for (int m = 0; m < LPT; ++m) { bd[nf][m] = INFINITY; bi[nf][m] = 0x7fffffff; }

    const int strow = tid >> 3;              // 0..31
    const int stk8  = (tid & 7) * 8;         // k offset 0,8,..,56

    for (int t = 0; t < TILES_PER_CHUNK; ++t) {
        const int ytile0 = ybase + t * BM;

        f32x4 acc[4][4];
#pragma unroll
        for (int i = 0; i < 4; ++i)
#pragma unroll
            for (int j = 0; j < 4; ++j)
                acc[i][j] = (f32x4){0.f, 0.f, 0.f, 0.f};

        for (int kc = 0; kc < DIM; kc += BK) {
            __syncthreads();
            if (kc == 0 && tid < 128) ysq_s[tid] = ysq[ytile0 + tid];
#pragma unroll
            for (int p = 0; p < 4; ++p) {
                const int row = p * 32 + strow;
                const float* ag = Y + (size_t)(ytile0 + row) * DIM + kc + stk8;
                float4 a0 = *(const float4*)ag;
                float4 a1 = *(const float4*)(ag + 4);
                bf16x8 ha;
                ha[0] = (short)f2b(a0.x); ha[1] = (short)f2b(a0.y);
                ha[2] = (short)f2b(a0.z); ha[3] = (short)f2b(a0.w);
                ha[4] = (short)f2b(a1.x); ha[5] = (short)f2b(a1.y);
                ha[6] = (short)f2b(a1.z); ha[7] = (short)f2b(a1.w);
                *(bf16x8*)(As + row * ST + stk8 * 2) = ha;

                const float* bg = X + (size_t)(row0 + row) * DIM + kc + stk8;
                float4 b0 = *(const float4*)bg;
                float4 b1 = *(const float4*)(bg + 4);
                bf16x8 hb;
                hb[0] = (short)f2b(b0.x); hb[1] = (short)f2b(b0.y);
                hb[2] = (short)f2b(b0.z); hb[3] = (short)f2b(b0.w);
                hb[4] = (short)f2b(b1.x); hb[5] = (short)f2b(b1.y);
                hb[6] = (short)f2b(b1.z); hb[7] = (short)f2b(b1.w);
                *(bf16x8*)(Bs + row * ST + stk8 * 2) = hb;
            }
            __syncthreads();

#pragma unroll
            for (int kk = 0; kk < BK; kk += 32) {
                const int kb = (kk + lg * 8) * 2;
                bf16x8 af[4], bf[4];
#pragma unroll
                for (int mf = 0; mf < 4; ++mf)
                    af[mf] = *(const bf16x8*)(As + (m0 + mf * 16 + l15) * ST + kb);
#pragma unroll
                for (int nf = 0; nf < 4; ++nf)
                    bf[nf] = *(const bf16x8*)(Bs + (n0 + nf * 16 + l15) * ST + kb);
#pragma unroll
                for (int mf = 0; mf < 4; ++mf)
#pragma unroll
                    for (int nf = 0; nf < 4; ++nf)
                        acc[mf][nf] = __builtin_amdgcn_mfma_f32_16x16x32_bf16(
                            af[mf], bf[nf], acc[mf][nf], 0, 0, 0);
            }
        }

#pragma unroll
        for (int mf = 0; mf < 4; ++mf) {
            float yq[4];
#pragma unroll
            for (int j = 0; j < 4; ++j)
                yq[j] = ysq_s[m0 + mf * 16 + lg * 4 + j];
#pragma unroll
            for (int nf = 0; nf < 4; ++nf) {
#pragma unroll
                for (int j = 0; j < 4; ++j) {
                    const float d = yq[j] - 2.f * acc[mf][nf][j];
                    const int  gi = ytile0 + m0 + mf * 16 + lg * 4 + j;
                    push<LPT>(d, gi, bd[nf], bi[nf]);
                }
            }
        }
    }

    __syncthreads();
    const int slot = (wv >> 1) * 4 + lg;     // 0..7
#pragma unroll
    for (int nf = 0; nf < 4; ++nf) {
        const int r = n0 + nf * 16 + l15;
#pragma unroll
        for (int e = 0; e < LPT; ++e) {
            *(float*)(smem + r * 512 + slot * 64 + e * 8)     = bd[nf][e];
            *(int*)  (smem + r * 512 + slot * 64 + e * 8 + 4) = bi[nf][e];
        }
    }
    __syncthreads();
    if (tid < 128) {
        float md[KEEP]; int mi[KEEP];
#pragma unroll
        for (int m = 0; m < KEEP; ++m) { md[m] = INFINITY; mi[m] = 0x7fffffff; }
        for (int s = 0; s < 8; ++s)
#pragma unroll
            for (int e = 0; e < LPT; ++e) {
                float d = *(const float*)(smem + tid * 512 + s * 64 + e * 8);
                int   i = *(const int*)  (smem + tid * 512 + s * 64 + e * 8 + 4);
                push<KEEP>(d, i, md, mi);
            }
        const int row = row0 + tid;
        const size_t o = (size_t)row * NCAND + chunk * KEEP;
#pragma unroll
        for (int m = 0; m < KEEP; ++m) { cand_d[o + m] = md[m]; cand_i[o + m] = mi[m]; }
    }
}

// Rescore v2: coarse top-32 of 128 candidates, then distances recomputed
// BIT-EXACTLY as round 1's verified path: fp32 FMA in ascending-k order
// within 64-wide chunks, chunk sums accumulated in fp64 in chunk order,
// final (float)((double)ysq - 2.0*acc64). One thread per (row, candidate).
__global__ __launch_bounds__(256) void knn_rescore(
        const float* __restrict__ X, const float* __restrict__ Y,
        const float* __restrict__ ysq,
        const float* __restrict__ cand_d, const int* __restrict__ cand_i,
        int* __restrict__ out) {
    __shared__ float cd[8][NCAND];
    __shared__ int   ci[8][NCAND];
    __shared__ int   rci[8][RESC];
    __shared__ float rd[8][RESC];

    const int tid  = threadIdx.x;
    const int row0 = blockIdx.x * 8;

    // stage 8 rows x 128 candidates
#pragma unroll
    for (int q = 0; q < 4; ++q) {
        const int idx = q * 256 + tid;       // 0..1023
        const int r = idx >> 7, j = idx & 127;
        cd[r][j] = cand_d[(size_t)(row0 + r) * NCAND + j];
        ci[r][j] = cand_i[(size_t)(row0 + r) * NCAND + j];
    }
    __syncthreads();

    // per-row coarse top-32 (serial, 8 threads)
    if (tid < 8) {
        float md[RESC]; int mi[RESC];
#pragma unroll
        for (int m = 0; m < RESC; ++m) { md[m] = INFINITY; mi[m] = 0x7fffffff; }
        for (int j = 0; j < NCAND; ++j) push<RESC>(cd[tid][j], ci[tid][j], md, mi);
#pragma unroll
        for (int m = 0; m < RESC; ++m) rci[tid][m] = mi[m];
    }
    __syncthreads();

    // exact rescore: thread (r = tid>>5, c = tid&31)
    {
        const int r = tid >> 5, c = tid & 31;
        const int row = row0 + r;
        const int yi = rci[r][c];
        const float* xr = X + (size_t)row * DIM;
        const float* yr = Y + (size_t)yi * DIM;
        double acc64 = 0.0;
        for (int kc = 0; kc < DIM; kc += 64) {
            float acc = 0.f;
#pragma unroll
            for (int k4 = 0; k4 < 16; ++k4) {
                float4 xv = *(const float4*)(xr + kc + k4 * 4);
                float4 yv = *(const float4*)(yr + kc + k4 * 4);
                acc = fmaf(xv.x, yv.x, acc);
                acc = fmaf(xv.y, yv.y, acc);
                acc = fmaf(xv.z, yv.z, acc);
                acc = fmaf(xv.w, yv.w, acc);
            }
            acc64 += (double)acc;
        }
        rd[r][c] = (float)((double)ysq[yi] - 2.0 * acc64);
    }
    __syncthreads();

    // final exact top-8 per row
    if (tid < 8) {
        float fd[KNN]; int fi[KNN];
#pragma unroll
        for (int m = 0; m < KNN; ++m) { fd[m] = INFINITY; fi[m] = 0x7fffffff; }
        for (int j = 0; j < RESC; ++j) push<KNN>(rd[tid][j], rci[tid][j], fd, fi);
        const int row = row0 + tid;
#pragma unroll
        for (int m = 0; m < KNN; ++m) out[row * KNN + m] = fi[m];
    }
}

extern "C" void kernel_launch(void* const* d_in, const int* in_sizes, int n_in,
                              void* d_out, int out_size, void* d_ws, size_t ws_size,
                              hipStream_t stream) {
    const float* X = (const float*)d_in[0];   // [8192, 512]
    const float* Y = (const float*)d_in[1];   // [65536, 512]
    int* out = (int*)d_out;                   // [8192, 8] int32

    char* ws = (char*)d_ws;
    float* ysq    = (float*)ws;                                      // 256 KB
    float* cand_d = (float*)(ws + 262144);                           // 4 MB
    int*   cand_i = (int*)(ws + 262144 + (size_t)NX * NCAND * 4);    // 4 MB

    ysq_kernel<<<NY / 4, 256, 0, stream>>>(Y, ysq);

    dim3 g1(NCH, NX / BN);   // 8 x 64 = 512 blocks
    knn_coarse<<<g1, 256, 0, stream>>>(X, Y, ysq, cand_d, cand_i);

    knn_rescore<<<NX / 8, 256, 0, stream>>>(X, Y, ysq, cand_d, cand_i, out);
}

// Round 5
// 2529.580 us; speedup vs baseline: 8.6293x; 1.3808x over previous
//
#include <hip/hip_runtime.h>
#include <math.h>

#define NX 8192
#define NY 65536
#define DIM 512
#define KNN 8

#define BM 128                 // Y rows per tile (MFMA M side)
#define BN 128                 // X rows per block (MFMA N side)
#define BK 64                  // K step
#define NCH 8                  // Y chunks (grid.x)
#define COLS_PER_CHUNK (NY / NCH)            // 8192 Y rows per chunk
#define TILES_PER_CHUNK (COLS_PER_CHUNK / BM)  // 64
#define LPT 8                  // per-lane top-K per X-row
#define KEEP 16                // kept per (row, chunk)
#define NCAND (NCH * KEEP)     // 128 candidates per row
#define RESC 32                // rescored per row

#define ST 160                 // fallback LDS row stride (bytes)

typedef short bf16x8 __attribute__((ext_vector_type(8)));
typedef float f32x4 __attribute__((ext_vector_type(4)));

__device__ __forceinline__ unsigned short f2b(float f) {
    unsigned int u = __float_as_uint(f);
    u += 0x7FFFu + ((u >> 16) & 1u);       // RNE to bf16
    return (unsigned short)(u >> 16);
}

// ascending (d, idx) top-K insert, fully static indices
template <int K>
__device__ __forceinline__ void push(float d, int gi, float (&bd)[K], int (&bi)[K]) {
    if (d > bd[K - 1] || (d == bd[K - 1] && gi >= bi[K - 1])) return;
    bd[K - 1] = d; bi[K - 1] = gi;
#pragma unroll
    for (int p = K - 1; p > 0; --p) {
        bool sw = (bd[p] < bd[p - 1]) || (bd[p] == bd[p - 1] && bi[p] < bi[p - 1]);
        if (sw) {
            float td = bd[p]; bd[p] = bd[p - 1]; bd[p - 1] = td;
            int   ti = bi[p]; bi[p] = bi[p - 1]; bi[p - 1] = ti;
        }
    }
}

// fp32 -> bf16 (RNE) bulk convert, 8 elems/thread
__global__ void cvt_bf16_kernel(const float* __restrict__ src,
                                unsigned short* __restrict__ dst, int n8) {
    int i = blockIdx.x * blockDim.x + threadIdx.x;
    if (i >= n8) return;
    const float4* s = (const float4*)src;
    float4 a0 = s[i * 2], a1 = s[i * 2 + 1];
    bf16x8 h;
    h[0] = (short)f2b(a0.x); h[1] = (short)f2b(a0.y);
    h[2] = (short)f2b(a0.z); h[3] = (short)f2b(a0.w);
    h[4] = (short)f2b(a1.x); h[5] = (short)f2b(a1.y);
    h[6] = (short)f2b(a1.z); h[7] = (short)f2b(a1.w);
    *(bf16x8*)(dst + (size_t)i * 8) = h;
}

// ||y||^2 per Y row, fp64 accumulate, one wave per row. (verified)
__global__ void ysq_kernel(const float* __restrict__ Y, float* __restrict__ ysq) {
    int row  = (blockIdx.x * blockDim.x + threadIdx.x) >> 6;
    int lane = threadIdx.x & 63;
    if (row >= NY) return;
    const float4* yr = reinterpret_cast<const float4*>(Y + (size_t)row * DIM);
    double s = 0.0;
#pragma unroll
    for (int i = 0; i < 2; ++i) {
        float4 v = yr[lane + 64 * i];
        s += (double)v.x * v.x + (double)v.y * v.y + (double)v.z * v.z + (double)v.w * v.w;
    }
#pragma unroll
    for (int off = 32; off > 0; off >>= 1) s += __shfl_xor(s, off, 64);
    if (lane == 0) ysq[row] = (float)s;
}

// ---------- fast coarse: bf16 inputs, global_load_lds, swizzled-source ----------
__global__ __launch_bounds__(256, 2) void knn_coarse_fast(
        const unsigned short* __restrict__ Xb, const unsigned short* __restrict__ Yb,
        const float* __restrict__ ysq,
        float* __restrict__ cand_d, int* __restrict__ cand_i) {
    // [0,16K) As = Y tile [128 rows][128 B], swizzled chunks; [16K,32K) Bs = X tile;
    // [32K,32K+512) ysq_s.  After tile loop the full 64 KB is the merge buffer.
    __shared__ __align__(16) char smem[65536];
    char* As = smem;
    char* Bs = smem + 16384;
    float* ysq_s = (float*)(smem + 32768);

    const int tid  = threadIdx.x;
    const int lane = tid & 63;
    const int w    = tid >> 6;
    const int chunk = blockIdx.x;            // 0..7
    const int row0  = blockIdx.y * BN;       // X rows of this block
    const int ybase = chunk * COLS_PER_CHUNK;
    const int m0 = (w >> 1) * 64;            // wave quadrant: Y side
    const int n0 = (w & 1) * 64;             //                X side
    const int l15 = lane & 15;
    const int lg  = lane >> 4;               // 0..3

    // staging geometry: lane covers 16 B; row-in-8-group = lane>>3, chunk = lane&7
    const int srow = lane >> 3;                     // 0..7
    const int scb  = ((lane & 7) ^ srow) << 4;      // swizzled source chunk (bytes)
    // per-lane global base for X rows (constant over t)
    const char* pX = (const char*)Xb + (size_t)(row0 + w * 32 + srow) * (DIM * 2) + scb;

    float bd[4][LPT]; int bi[4][LPT];
#pragma unroll
    for (int nf = 0; nf < 4; ++nf)
#pragma unroll
        for (int m = 0; m < LPT; ++m) { bd[nf][m] = INFINITY; bi[nf][m] = 0x7fffffff; }

    for (int t = 0; t < TILES_PER_CHUNK; ++t) {
        const int ytile0 = ybase + t * BM;
        const char* pY = (const char*)Yb + (size_t)(ytile0 + w * 32 + srow) * (DIM * 2) + scb;

        f32x4 acc[4][4];
#pragma unroll
        for (int i = 0; i < 4; ++i)
#pragma unroll
            for (int j = 0; j < 4; ++j)
                acc[i][j] = (f32x4){0.f, 0.f, 0.f, 0.f};

        for (int kc = 0; kc < DIM; kc += BK) {
            __syncthreads();   // prior frag reads done before restaging
            if (kc == 0 && tid < 128) ysq_s[tid] = ysq[ytile0 + tid];
#pragma unroll
            for (int q = 0; q < 4; ++q) {
                // wave stages rows w*32+q*8 .. +8 (1 KB per inst, lane l -> +16*l)
                __builtin_amdgcn_global_load_lds(
                    (const __attribute__((address_space(1))) void*)(pY + q * 8 * (DIM * 2) + kc * 2),
                    (__attribute__((address_space(3))) void*)(As + w * 4096 + q * 1024),
                    16, 0, 0);
                __builtin_amdgcn_global_load_lds(
                    (const __attribute__((address_space(1))) void*)(pX + q * 8 * (DIM * 2) + kc * 2),
                    (__attribute__((address_space(3))) void*)(Bs + w * 4096 + q * 1024),
                    16, 0, 0);
            }
            __syncthreads();

#pragma unroll
            for (int kk = 0; kk < BK; kk += 32) {
                const int kb = (kk + lg * 8) * 2;   // byte offset of lane's k slot
                bf16x8 af[4], bf[4];
#pragma unroll
                for (int mf = 0; mf < 4; ++mf) {
                    const int rr = m0 + mf * 16 + l15;
                    af[mf] = *(const bf16x8*)(As + rr * 128 + (kb ^ ((rr & 7) << 4)));
                }
#pragma unroll
                for (int nf = 0; nf < 4; ++nf) {
                    const int cc = n0 + nf * 16 + l15;
                    bf[nf] = *(const bf16x8*)(Bs + cc * 128 + (kb ^ ((cc & 7) << 4)));
                }
#pragma unroll
                for (int mf = 0; mf < 4; ++mf)
#pragma unroll
                    for (int nf = 0; nf < 4; ++nf)
                        acc[mf][nf] = __builtin_amdgcn_mfma_f32_16x16x32_bf16(
                            af[mf], bf[nf], acc[mf][nf], 0, 0, 0);
            }
        }

        // push distances straight from acc: C/D row = Y idx, col = X row
#pragma unroll
        for (int mf = 0; mf < 4; ++mf) {
            float yq[4];
#pragma unroll
            for (int j = 0; j < 4; ++j)
                yq[j] = ysq_s[m0 + mf * 16 + lg * 4 + j];
#pragma unroll
            for (int nf = 0; nf < 4; ++nf) {
#pragma unroll
                for (int j = 0; j < 4; ++j) {
                    const float d = yq[j] - 2.f * acc[mf][nf][j];
                    const int  gi = ytile0 + m0 + mf * 16 + lg * 4 + j;
                    push<LPT>(d, gi, bd[nf], bi[nf]);
                }
            }
        }
    }

    // merge the 8 lane-lists per X row via LDS (reuses all 64 KB)
    __syncthreads();
    const int slot = (w >> 1) * 4 + lg;      // 0..7
#pragma unroll
    for (int nf = 0; nf < 4; ++nf) {
        const int r = n0 + nf * 16 + l15;
#pragma unroll
        for (int e = 0; e < LPT; ++e) {
            *(float*)(smem + r * 512 + slot * 64 + e * 8)     = bd[nf][e];
            *(int*)  (smem + r * 512 + slot * 64 + e * 8 + 4) = bi[nf][e];
        }
    }
    __syncthreads();
    if (tid < 128) {
        float md[KEEP]; int mi[KEEP];
#pragma unroll
        for (int m = 0; m < KEEP; ++m) { md[m] = INFINITY; mi[m] = 0x7fffffff; }
        for (int s = 0; s < 8; ++s)
#pragma unroll
            for (int e = 0; e < LPT; ++e) {
                float d = *(const float*)(smem + tid * 512 + s * 64 + e * 8);
                int   i = *(const int*)  (smem + tid * 512 + s * 64 + e * 8 + 4);
                push<KEEP>(d, i, md, mi);
            }
        const int row = row0 + tid;
        const size_t o = (size_t)row * NCAND + chunk * KEEP;
#pragma unroll
        for (int m = 0; m < KEEP; ++m) { cand_d[o + m] = md[m]; cand_i[o + m] = mi[m]; }
    }
}

// ---------- fallback coarse (round-4, proven) ----------
__global__ __launch_bounds__(256, 2) void knn_coarse_fb(
        const float* __restrict__ X, const float* __restrict__ Y,
        const float* __restrict__ ysq,
        float* __restrict__ cand_d, int* __restrict__ cand_i) {
    __shared__ __align__(16) char smem[65536];
    char* As = smem;
    char* Bs = smem + 20480;
    float* ysq_s = (float*)(smem + 40960);

    const int tid  = threadIdx.x;
    const int lane = tid & 63;
    const int wv   = tid >> 6;
    const int chunk = blockIdx.x;
    const int row0  = blockIdx.y * BN;
    const int ybase = chunk * COLS_PER_CHUNK;
    const int m0 = (wv >> 1) * 64;
    const int n0 = (wv & 1) * 64;
    const int l15 = lane & 15;
    const int lg  = lane >> 4;

    float bd[4][LPT]; int bi[4][LPT];
#pragma unroll
    for (int nf = 0; nf < 4; ++nf)
#pragma unroll
        for (int m = 0; m < LPT; ++m) { bd[nf][m] = INFINITY; bi[nf][m] = 0x7fffffff; }

    const int strow = tid >> 3;
    const int stk8  = (tid & 7) * 8;

    for (int t = 0; t < TILES_PER_CHUNK; ++t) {
        const int ytile0 = ybase + t * BM;
        f32x4 acc[4][4];
#pragma unroll
        for (int i = 0; i < 4; ++i)
#pragma unroll
            for (int j = 0; j < 4; ++j) acc[i][j] = (f32x4){0.f, 0.f, 0.f, 0.f};

        for (int kc = 0; kc < DIM; kc += BK) {
            __syncthreads();
            if (kc == 0 && tid < 128) ysq_s[tid] = ysq[ytile0 + tid];
#pragma unroll
            for (int p = 0; p < 4; ++p) {
                const int row = p * 32 + strow;
                const float* ag = Y + (size_t)(ytile0 + row) * DIM + kc + stk8;
                float4 a0 = *(const float4*)ag;
                float4 a1 = *(const float4*)(ag + 4);
                bf16x8 ha;
                ha[0] = (short)f2b(a0.x); ha[1] = (short)f2b(a0.y);
                ha[2] = (short)f2b(a0.z); ha[3] = (short)f2b(a0.w);
                ha[4] = (short)f2b(a1.x); ha[5] = (short)f2b(a1.y);
                ha[6] = (short)f2b(a1.z); ha[7] = (short)f2b(a1.w);
                *(bf16x8*)(As + row * ST + stk8 * 2) = ha;

                const float* bg = X + (size_t)(row0 + row) * DIM + kc + stk8;
                float4 b0 = *(const float4*)bg;
                float4 b1 = *(const float4*)(bg + 4);
                bf16x8 hb;
                hb[0] = (short)f2b(b0.x); hb[1] = (short)f2b(b0.y);
                hb[2] = (short)f2b(b0.z); hb[3] = (short)f2b(b0.w);
                hb[4] = (short)f2b(b1.x); hb[5] = (short)f2b(b1.y);
                hb[6] = (short)f2b(b1.z); hb[7] = (short)f2b(b1.w);
                *(bf16x8*)(Bs + row * ST + stk8 * 2) = hb;
            }
            __syncthreads();

#pragma unroll
            for (int kk = 0; kk < BK; kk += 32) {
                const int kb = (kk + lg * 8) * 2;
                bf16x8 af[4], bf[4];
#pragma unroll
                for (int mf = 0; mf < 4; ++mf)
                    af[mf] = *(const bf16x8*)(As + (m0 + mf * 16 + l15) * ST + kb);
#pragma unroll
                for (int nf = 0; nf < 4; ++nf)
                    bf[nf] = *(const bf16x8*)(Bs + (n0 + nf * 16 + l15) * ST + kb);
#pragma unroll
                for (int mf = 0; mf < 4; ++mf)
#pragma unroll
                    for (int nf = 0; nf < 4; ++nf)
                        acc[mf][nf] = __builtin_amdgcn_mfma_f32_16x16x32_bf16(
                            af[mf], bf[nf], acc[mf][nf], 0, 0, 0);
            }
        }

#pragma unroll
        for (int mf = 0; mf < 4; ++mf) {
            float yq[4];
#pragma unroll
            for (int j = 0; j < 4; ++j) yq[j] = ysq_s[m0 + mf * 16 + lg * 4 + j];
#pragma unroll
            for (int nf = 0; nf < 4; ++nf)
#pragma unroll
                for (int j = 0; j < 4; ++j) {
                    const float d = yq[j] - 2.f * acc[mf][nf][j];
                    const int  gi = ytile0 + m0 + mf * 16 + lg * 4 + j;
                    push<LPT>(d, gi, bd[nf], bi[nf]);
                }
        }
    }

    __syncthreads();
    const int slot = (wv >> 1) * 4 + lg;
#pragma unroll
    for (int nf = 0; nf < 4; ++nf) {
        const int r = n0 + nf * 16 + l15;
#pragma unroll
        for (int e = 0; e < LPT; ++e) {
            *(float*)(smem + r * 512 + slot * 64 + e * 8)     = bd[nf][e];
            *(int*)  (smem + r * 512 + slot * 64 + e * 8 + 4) = bi[nf][e];
        }
    }
    __syncthreads();
    if (tid < 128) {
        float md[KEEP]; int mi[KEEP];
#pragma unroll
        for (int m = 0; m < KEEP; ++m) { md[m] = INFINITY; mi[m] = 0x7fffffff; }
        for (int s = 0; s < 8; ++s)
#pragma unroll
            for (int e = 0; e < LPT; ++e) {
                float d = *(const float*)(smem + tid * 512 + s * 64 + e * 8);
                int   i = *(const int*)  (smem + tid * 512 + s * 64 + e * 8 + 4);
                push<KEEP>(d, i, md, mi);
            }
        const int row = row0 + tid;
        const size_t o = (size_t)row * NCAND + chunk * KEEP;
#pragma unroll
        for (int m = 0; m < KEEP; ++m) { cand_d[o + m] = md[m]; cand_i[o + m] = mi[m]; }
    }
}

// Rescore: coarse top-32 of 128 candidates, then BIT-EXACT round-1 arithmetic.
__global__ __launch_bounds__(256) void knn_rescore(
        const float* __restrict__ X, const float* __restrict__ Y,
        const float* __restrict__ ysq,
        const float* __restrict__ cand_d, const int* __restrict__ cand_i,
        int* __restrict__ out) {
    __shared__ float cd[8][NCAND];
    __shared__ int   ci[8][NCAND];
    __shared__ int   rci[8][RESC];
    __shared__ float rd[8][RESC];

    const int tid  = threadIdx.x;
    const int row0 = blockIdx.x * 8;

#pragma unroll
    for (int q = 0; q < 4; ++q) {
        const int idx = q * 256 + tid;
        const int r = idx >> 7, j = idx & 127;
        cd[r][j] = cand_d[(size_t)(row0 + r) * NCAND + j];
        ci[r][j] = cand_i[(size_t)(row0 + r) * NCAND + j];
    }
    __syncthreads();

    if (tid < 8) {
        float md[RESC]; int mi[RESC];
#pragma unroll
        for (int m = 0; m < RESC; ++m) { md[m] = INFINITY; mi[m] = 0x7fffffff; }
        for (int j = 0; j < NCAND; ++j) push<RESC>(cd[tid][j], ci[tid][j], md, mi);
#pragma unroll
        for (int m = 0; m < RESC; ++m) rci[tid][m] = mi[m];
    }
    __syncthreads();

    {
        const int r = tid >> 5, c = tid & 31;
        const int row = row0 + r;
        const int yi = rci[r][c];
        const float* xr = X + (size_t)row * DIM;
        const float* yr = Y + (size_t)yi * DIM;
        double acc64 = 0.0;
        for (int kc = 0; kc < DIM; kc += 64) {
            float acc = 0.f;
#pragma unroll
            for (int k4 = 0; k4 < 16; ++k4) {
                float4 xv = *(const float4*)(xr + kc + k4 * 4);
                float4 yv = *(const float4*)(yr + kc + k4 * 4);
                acc = fmaf(xv.x, yv.x, acc);
                acc = fmaf(xv.y, yv.y, acc);
                acc = fmaf(xv.z, yv.z, acc);
                acc = fmaf(xv.w, yv.w, acc);
            }
            acc64 += (double)acc;
        }
        rd[r][c] = (float)((double)ysq[yi] - 2.0 * acc64);
    }
    __syncthreads();

    if (tid < 8) {
        float fd[KNN]; int fi[KNN];
#pragma unroll
        for (int m = 0; m < KNN; ++m) { fd[m] = INFINITY; fi[m] = 0x7fffffff; }
        for (int j = 0; j < RESC; ++j) push<KNN>(rd[tid][j], rci[tid][j], fd, fi);
        const int row = row0 + tid;
#pragma unroll
        for (int m = 0; m < KNN; ++m) out[row * KNN + m] = fi[m];
    }
}

extern "C" void kernel_launch(void* const* d_in, const int* in_sizes, int n_in,
                              void* d_out, int out_size, void* d_ws, size_t ws_size,
                              hipStream_t stream) {
    const float* X = (const float*)d_in[0];   // [8192, 512]
    const float* Y = (const float*)d_in[1];   // [65536, 512]
    int* out = (int*)d_out;                   // [8192, 8] int32

    char* ws = (char*)d_ws;
    float* ysq    = (float*)ws;                                   // 256 KB
    float* cand_d = (float*)(ws + 262144);                        // 4 MB
    int*   cand_i = (int*)(ws + 262144 + (size_t)NX * NCAND * 4); // 4 MB
    size_t off = 262144 + 2 * (size_t)NX * NCAND * 4;             // 8.65 MB
    unsigned short* Xbf = (unsigned short*)(ws + off);            // 8 MB
    unsigned short* Ybf = (unsigned short*)(ws + off + (size_t)NX * DIM * 2);  // 64 MB
    const size_t need = off + (size_t)(NX + NY) * DIM * 2;

    ysq_kernel<<<NY / 4, 256, 0, stream>>>(Y, ysq);

    dim3 g1(NCH, NX / BN);   // 8 x 64 = 512 blocks
    if (ws_size >= need) {
        cvt_bf16_kernel<<<(NX * DIM / 8) / 256, 256, 0, stream>>>(X, Xbf, NX * DIM / 8);
        cvt_bf16_kernel<<<(NY * DIM / 8) / 256, 256, 0, stream>>>(Y, Ybf, NY * DIM / 8);
        knn_coarse_fast<<<g1, 256, 0, stream>>>(Xbf, Ybf, ysq, cand_d, cand_i);
    } else {
        knn_coarse_fb<<<g1, 256, 0, stream>>>(X, Y, ysq, cand_d, cand_i);
    }

    knn_rescore<<<NX / 8, 256, 0, stream>>>(X, Y, ysq, cand_d, cand_i, out);
}

// Round 6
// 1743.505 us; speedup vs baseline: 12.5199x; 1.4509x over previous
//
#include <hip/hip_runtime.h>
#include <math.h>

#define NX 8192
#define NY 65536
#define DIM 512
#define KNN 8

#define BM 128                 // Y rows per tile (MFMA M side)
#define BN 128                 // X rows per block (MFMA N side)
#define BK 64                  // K step
#define NCH 8                  // Y chunks per pass (grid.x)
#define NPASS 2                // sequential Y passes (Y slice/XCD -> 4 MB, L2-fits)
#define ROWS_PER_PASS (NY / NPASS)            // 32768
#define COLS_PER_CHUNK (ROWS_PER_PASS / NCH)  // 4096 Y rows per chunk
#define TILES_PER_CHUNK (COLS_PER_CHUNK / BM) // 32
#define LPT 8                  // per-lane top-K per X-row (packed keys)
#define KEEP 16                // kept per (row, chunk)
#define NCAND (NPASS * NCH * KEEP)   // 256 candidates per row
#define RESC 32                // rescored per row

typedef short bf16x8 __attribute__((ext_vector_type(8)));
typedef float f32x4 __attribute__((ext_vector_type(4)));

__device__ __forceinline__ unsigned short f2b(float f) {
    unsigned int u = __float_as_uint(f);
    u += 0x7FFFu + ((u >> 16) & 1u);       // RNE to bf16
    return (unsigned short)(u >> 16);
}

// ascending (d, idx) top-K insert, fully static indices
template <int K>
__device__ __forceinline__ void push(float d, int gi, float (&bd)[K], int (&bi)[K]) {
    if (d > bd[K - 1] || (d == bd[K - 1] && gi >= bi[K - 1])) return;
    bd[K - 1] = d; bi[K - 1] = gi;
#pragma unroll
    for (int p = K - 1; p > 0; --p) {
        bool sw = (bd[p] < bd[p - 1]) || (bd[p] == bd[p - 1] && bi[p] < bi[p - 1]);
        if (sw) {
            float td = bd[p]; bd[p] = bd[p - 1]; bd[p - 1] = td;
            int   ti = bi[p]; bi[p] = bi[p - 1]; bi[p - 1] = ti;
        }
    }
}

// ascending top-K insert on packed uint32 keys ((dq<<16)|gi) — one compare/reject
template <int K>
__device__ __forceinline__ void pushk(unsigned int k, unsigned int (&lst)[K]) {
    if (k >= lst[K - 1]) return;
    lst[K - 1] = k;
#pragma unroll
    for (int p = K - 1; p > 0; --p) {
        if (lst[p] < lst[p - 1]) {
            unsigned int t = lst[p]; lst[p] = lst[p - 1]; lst[p - 1] = t;
        }
    }
}

// fp32 -> bf16 (RNE) bulk convert, 8 elems/thread
__global__ void cvt_bf16_kernel(const float* __restrict__ src,
                                unsigned short* __restrict__ dst, int n8) {
    int i = blockIdx.x * blockDim.x + threadIdx.x;
    if (i >= n8) return;
    const float4* s = (const float4*)src;
    float4 a0 = s[i * 2], a1 = s[i * 2 + 1];
    bf16x8 h;
    h[0] = (short)f2b(a0.x); h[1] = (short)f2b(a0.y);
    h[2] = (short)f2b(a0.z); h[3] = (short)f2b(a0.w);
    h[4] = (short)f2b(a1.x); h[5] = (short)f2b(a1.y);
    h[6] = (short)f2b(a1.z); h[7] = (short)f2b(a1.w);
    *(bf16x8*)(dst + (size_t)i * 8) = h;
}

// ||y||^2 per Y row, fp64 accumulate, one wave per row. (verified)
__global__ void ysq_kernel(const float* __restrict__ Y, float* __restrict__ ysq) {
    int row  = (blockIdx.x * blockDim.x + threadIdx.x) >> 6;
    int lane = threadIdx.x & 63;
    if (row >= NY) return;
    const float4* yr = reinterpret_cast<const float4*>(Y + (size_t)row * DIM);
    double s = 0.0;
#pragma unroll
    for (int i = 0; i < 2; ++i) {
        float4 v = yr[lane + 64 * i];
        s += (double)v.x * v.x + (double)v.y * v.y + (double)v.z * v.z + (double)v.w * v.w;
    }
#pragma unroll
    for (int off = 32; off > 0; off >>= 1) s += __shfl_xor(s, off, 64);
    if (lane == 0) ysq[row] = (float)s;
}

// Coarse: G = Y_tile . X^T via bf16 MFMA (global_load_lds, swizzled source);
// per-lane packed-key top-8 lists; two-pass LDS merge -> top-16 per (row,chunk).
__global__ __launch_bounds__(256, 3) void knn_coarse_fast(
        const unsigned short* __restrict__ Xb, const unsigned short* __restrict__ Yb,
        const float* __restrict__ ysq,
        unsigned int* __restrict__ cand_k, int ypass) {
    // [0,16K) As = Y tile [128 rows][128 B] (source-swizzled); [16K,32K) Bs = X;
    // [32K,32K+512) ysq_s. Merge reuses [0,16896).
    __shared__ __align__(16) char smem[33280];
    char* As = smem;
    char* Bs = smem + 16384;
    float* ysq_s = (float*)(smem + 32768);

    const int tid  = threadIdx.x;
    const int lane = tid & 63;
    const int w    = tid >> 6;
    const int chunk = blockIdx.x;            // 0..7
    const int row0  = blockIdx.y * BN;       // X rows of this block
    const int ybase = ypass * ROWS_PER_PASS + chunk * COLS_PER_CHUNK;
    const int m0 = (w >> 1) * 64;            // wave quadrant: Y side
    const int n0 = (w & 1) * 64;             //                X side
    const int l15 = lane & 15;
    const int lg  = lane >> 4;               // 0..3

    // staging geometry (verified round 5): lane covers 16 B
    const int srow = lane >> 3;                     // 0..7
    const int scb  = ((lane & 7) ^ srow) << 4;      // swizzled source chunk (bytes)
    const char* pX = (const char*)Xb + (size_t)(row0 + w * 32 + srow) * (DIM * 2) + scb;

    // kb_[nf][*]: packed-key top-8 for X row n0+nf*16+l15 over this lane's Y strata
    unsigned int kb_[4][LPT];
#pragma unroll
    for (int nf = 0; nf < 4; ++nf)
#pragma unroll
        for (int m = 0; m < LPT; ++m) kb_[nf][m] = 0xffffffffu;

    for (int t = 0; t < TILES_PER_CHUNK; ++t) {
        const int ytile0 = ybase + t * BM;
        const char* pY = (const char*)Yb + (size_t)(ytile0 + w * 32 + srow) * (DIM * 2) + scb;

        f32x4 acc[4][4];
#pragma unroll
        for (int i = 0; i < 4; ++i)
#pragma unroll
            for (int j = 0; j < 4; ++j)
                acc[i][j] = (f32x4){0.f, 0.f, 0.f, 0.f};

        for (int kc = 0; kc < DIM; kc += BK) {
            __syncthreads();   // prior frag/ysq_s reads done before restaging
            if (kc == 0 && tid < 128) ysq_s[tid] = ysq[ytile0 + tid];
#pragma unroll
            for (int q = 0; q < 4; ++q) {
                __builtin_amdgcn_global_load_lds(
                    (const __attribute__((address_space(1))) void*)(pY + q * 8 * (DIM * 2) + kc * 2),
                    (__attribute__((address_space(3))) void*)(As + w * 4096 + q * 1024),
                    16, 0, 0);
                __builtin_amdgcn_global_load_lds(
                    (const __attribute__((address_space(1))) void*)(pX + q * 8 * (DIM * 2) + kc * 2),
                    (__attribute__((address_space(3))) void*)(Bs + w * 4096 + q * 1024),
                    16, 0, 0);
            }
            __syncthreads();

#pragma unroll
            for (int kk = 0; kk < BK; kk += 32) {
                const int kb = (kk + lg * 8) * 2;   // byte offset of lane's k slot
                bf16x8 af[4], bf[4];
#pragma unroll
                for (int mf = 0; mf < 4; ++mf) {
                    const int rr = m0 + mf * 16 + l15;
                    af[mf] = *(const bf16x8*)(As + rr * 128 + (kb ^ ((rr & 7) << 4)));
                }
#pragma unroll
                for (int nf = 0; nf < 4; ++nf) {
                    const int cc = n0 + nf * 16 + l15;
                    bf[nf] = *(const bf16x8*)(Bs + cc * 128 + (kb ^ ((cc & 7) << 4)));
                }
#pragma unroll
                for (int mf = 0; mf < 4; ++mf)
#pragma unroll
                    for (int nf = 0; nf < 4; ++nf)
                        acc[mf][nf] = __builtin_amdgcn_mfma_f32_16x16x32_bf16(
                            af[mf], bf[nf], acc[mf][nf], 0, 0, 0);
            }
        }

        // pack distances into 32-bit keys: (trunc(d*32) << 16) | gi  (gi < 2^16)
#pragma unroll
        for (int mf = 0; mf < 4; ++mf) {
            const int gibase = ytile0 + m0 + mf * 16 + lg * 4;
            float yq32[4];
#pragma unroll
            for (int j = 0; j < 4; ++j)
                yq32[j] = ysq_s[m0 + mf * 16 + lg * 4 + j] * 32.f;
#pragma unroll
            for (int nf = 0; nf < 4; ++nf) {
#pragma unroll
                for (int j = 0; j < 4; ++j) {
                    float d32 = fmaf(acc[mf][nf][j], -64.f, yq32[j]);   // 32*(yq - 2*dot)
                    d32 = fminf(fmaxf(d32, 0.f), 65535.f);
                    const unsigned int key =
                        ((unsigned int)d32 << 16) | (unsigned int)(gibase + j);
                    pushk<LPT>(key, kb_[nf]);
                }
            }
        }
    }

    // two-pass merge (64 rows each) reusing As/Bs region: 64 x 66 dwords
    __syncthreads();
    unsigned int* mbuf = (unsigned int*)smem;
    const int slot = (w >> 1) * 4 + lg;      // 0..7
#pragma unroll
    for (int h = 0; h < 2; ++h) {
        if ((w & 1) == h) {
#pragma unroll
            for (int nf = 0; nf < 4; ++nf) {
                const int r = nf * 16 + l15;  // row within this half
#pragma unroll
                for (int e = 0; e < LPT; ++e)
                    mbuf[r * 66 + slot * 8 + e] = kb_[nf][e];
            }
        }
        __syncthreads();
        if (tid < 64) {
            unsigned int mk[KEEP];
#pragma unroll
            for (int m = 0; m < KEEP; ++m) mk[m] = 0xffffffffu;
            for (int s = 0; s < 8; ++s)
#pragma unroll
                for (int e = 0; e < LPT; ++e)
                    pushk<KEEP>(mbuf[tid * 66 + s * 8 + e], mk);
            const int row = row0 + h * 64 + tid;
            unsigned int* co = cand_k + (size_t)row * NCAND + (ypass * NCH + chunk) * KEEP;
#pragma unroll
            for (int m = 0; m < KEEP; ++m) co[m] = mk[m];
        }
        __syncthreads();
    }
}

// Rescore: coarse top-32 of 256 packed keys, then BIT-EXACT round-1 arithmetic.
__global__ __launch_bounds__(256) void knn_rescore(
        const float* __restrict__ X, const float* __restrict__ Y,
        const float* __restrict__ ysq,
        const unsigned int* __restrict__ cand_k,
        int* __restrict__ out) {
    __shared__ unsigned int ck[8][NCAND];
    __shared__ int   rci[8][RESC];
    __shared__ float rd[8][RESC];

    const int tid  = threadIdx.x;
    const int row0 = blockIdx.x * 8;

#pragma unroll
    for (int q = 0; q < 8; ++q) {
        const int idx = q * 256 + tid;       // 0..2047
        const int r = idx >> 8, j = idx & 255;
        ck[r][j] = cand_k[(size_t)(row0 + r) * NCAND + j];
    }
    __syncthreads();

    if (tid < 8) {
        unsigned int mk[RESC];
#pragma unroll
        for (int m = 0; m < RESC; ++m) mk[m] = 0xffffffffu;
        for (int j = 0; j < NCAND; ++j) pushk<RESC>(ck[tid][j], mk);
#pragma unroll
        for (int m = 0; m < RESC; ++m) rci[tid][m] = (int)(mk[m] & 0xffffu);
    }
    __syncthreads();

    {
        const int r = tid >> 5, c = tid & 31;
        const int row = row0 + r;
        const int yi = rci[r][c];
        const float* xr = X + (size_t)row * DIM;
        const float* yr = Y + (size_t)yi * DIM;
        double acc64 = 0.0;
        for (int kc = 0; kc < DIM; kc += 64) {
            float acc = 0.f;
#pragma unroll
            for (int k4 = 0; k4 < 16; ++k4) {
                float4 xv = *(const float4*)(xr + kc + k4 * 4);
                float4 yv = *(const float4*)(yr + kc + k4 * 4);
                acc = fmaf(xv.x, yv.x, acc);
                acc = fmaf(xv.y, yv.y, acc);
                acc = fmaf(xv.z, yv.z, acc);
                acc = fmaf(xv.w, yv.w, acc);
            }
            acc64 += (double)acc;
        }
        rd[r][c] = (float)((double)ysq[yi] - 2.0 * acc64);
    }
    __syncthreads();

    if (tid < 8) {
        float fd[KNN]; int fi[KNN];
#pragma unroll
        for (int m = 0; m < KNN; ++m) { fd[m] = INFINITY; fi[m] = 0x7fffffff; }
        for (int j = 0; j < RESC; ++j) push<KNN>(rd[tid][j], rci[tid][j], fd, fi);
        const int row = row0 + tid;
#pragma unroll
        for (int m = 0; m < KNN; ++m) out[row * KNN + m] = fi[m];
    }
}

extern "C" void kernel_launch(void* const* d_in, const int* in_sizes, int n_in,
                              void* d_out, int out_size, void* d_ws, size_t ws_size,
                              hipStream_t stream) {
    const float* X = (const float*)d_in[0];   // [8192, 512]
    const float* Y = (const float*)d_in[1];   // [65536, 512]
    int* out = (int*)d_out;                   // [8192, 8] int32

    char* ws = (char*)d_ws;
    float* ysq           = (float*)ws;                              // 256 KB
    unsigned int* cand_k = (unsigned int*)(ws + 262144);            // 8 MB
    size_t off = 262144 + (size_t)NX * NCAND * 4;                   // 8.25 MB
    unsigned short* Xbf = (unsigned short*)(ws + off);              // 8 MB
    unsigned short* Ybf = (unsigned short*)(ws + off + (size_t)NX * DIM * 2);  // 64 MB

    ysq_kernel<<<NY / 4, 256, 0, stream>>>(Y, ysq);
    cvt_bf16_kernel<<<(NX * DIM / 8) / 256, 256, 0, stream>>>(X, Xbf, NX * DIM / 8);
    cvt_bf16_kernel<<<(NY * DIM / 8) / 256, 256, 0, stream>>>(Y, Ybf, NY * DIM / 8);

    dim3 g1(NCH, NX / BN);   // 8 x 64 = 512 blocks per pass, all co-resident
    knn_coarse_fast<<<g1, 256, 0, stream>>>(Xbf, Ybf, ysq, cand_k, 0);
    knn_coarse_fast<<<g1, 256, 0, stream>>>(Xbf, Ybf, ysq, cand_k, 1);

    knn_rescore<<<NX / 8, 256, 0, stream>>>(X, Y, ysq, cand_k, out);
}